// Round 9
// baseline (1630.551 us; speedup 1.0000x reference)
//
#include <hip/hip_runtime.h>

// TemporalDilatedAttention on gfx950 — round 9
// vs R8: cooperative launch silently failed (output = poison). Same mega
// design, but grid sync is now a MANUAL persistent-grid barrier (atomic
// counter + agent-scope fences) with a plain <<<512,256>>> launch.
// Co-residency: __launch_bounds__(256,2) caps VGPR<=256 -> 8 waves/CU; LDS
// 2x32KB=64KB<=160KB -> 2 blocks/CU guaranteed -> all 512 blocks resident.
// Barrier counter zeroed via hipMemsetAsync each call (ws is re-poisoned).

#define DD    1024
#define TALL  16384

typedef _Float16 half8  __attribute__((ext_vector_type(8)));
typedef _Float16 half4v __attribute__((ext_vector_type(4)));
typedef float    floatx4 __attribute__((ext_vector_type(4)));
typedef unsigned int u32;
typedef unsigned long long u64;

// ---------------- workspace layout (bytes), ~139.3 MB ----------------
static const size_t OFF_WOT  = 0;          // 2 MB  Wo^T f16
static const size_t OFF_WV16 = 2097152;    // 2 MB
static const size_t OFF_WK16 = 4194304;    // 2 MB
static const size_t OFF_WQ16 = 6291456;    // 2 MB
static const size_t OFF_XB   = 8388608;    // 0.5 MB
static const size_t OFF_G    = 8912896;    // 2 MB  G[h][q][f] f16
static const size_t OFF_WVOT = 11010048;   // 8 MB  WVOT[j][h*1024+k] f16
static const size_t OFF_WQKT = 19398656;   // 8 MB  WQKT[h][f][d] f16
static const size_t OFF_BVWO = 27787264;   // 4 KB
static const size_t OFF_BQK  = 27791360;   // 16 KB
static const size_t OFF_CF   = 27807744;   // 256 KB cf[1024][64] f32
static const size_t OFF_PHR  = 28069888;   // 2 MB  PHred[q][hk] f16
static const size_t OFF_OPP  = 30167040;   // 8 MB  FO partials 8x256x1024 f32
static const size_t OFF_HB   = 38555648;   // 32 MB histb; phpart (64x256x1024 f16) aliases
static const size_t OFF_HT   = 72110080;   // 32 MB hist^T f16 [feat][t]
static const size_t OFF_S    = 105664512;  // 32 MB expS f16 [h][q][t]
static const size_t OFF_BAR  = 139218944;  // 64 B barrier counter

// ---------------- async global->LDS, 16B per lane ----------------
__device__ __forceinline__ void gl_lds16(const void* g, void* l) {
  __builtin_amdgcn_global_load_lds((const __attribute__((address_space(1))) u32*)g,
                                   (__attribute__((address_space(3))) u32*)l, 16, 0, 0);
}

// ---------------- manual grid barrier (all 512 blocks co-resident) --------
__device__ __forceinline__ void gsync(u32* bar, u32 tgt, int tid) {
  __threadfence();                 // release this thread's writes (agent scope)
  __syncthreads();
  if (tid == 0) {
    __hip_atomic_fetch_add(bar, 1u, __ATOMIC_ACQ_REL, __HIP_MEMORY_SCOPE_AGENT);
    while (__hip_atomic_load(bar, __ATOMIC_ACQUIRE, __HIP_MEMORY_SCOPE_AGENT) < tgt)
      __builtin_amdgcn_s_sleep(2);
  }
  __syncthreads();
  __threadfence();                 // acquire: invalidate stale cached lines
}

// ---------------- prep (standalone launch; full occupancy BW) ------------
__global__ void prep_kernel(const float* __restrict__ Wo, const float* __restrict__ Wv,
                            const float* __restrict__ Wk, const float* __restrict__ Wq,
                            const float* __restrict__ x, const float* __restrict__ hist,
                            _Float16* __restrict__ WoT, _Float16* __restrict__ Wv16,
                            _Float16* __restrict__ Wk16, _Float16* __restrict__ Wq16,
                            _Float16* __restrict__ xb, _Float16* __restrict__ histb,
                            _Float16* __restrict__ histT) {
  int bid = blockIdx.x, tid = threadIdx.x;
  if (bid < 1024) {
    int k0 = (bid & 31) * 32, n0 = (bid >> 5) * 32;
    __shared__ float t32[32][33];
    int tx = tid & 31, ty = tid >> 5;
#pragma unroll
    for (int i = 0; i < 4; i++) {
      int r = ty + i * 8;
      t32[r][tx] = Wo[(size_t)(k0 + r) * DD + n0 + tx];
    }
    __syncthreads();
#pragma unroll
    for (int i = 0; i < 4; i++) {
      int r = ty + i * 8;
      WoT[(size_t)(n0 + r) * DD + k0 + tx] = (_Float16)t32[tx][r];
    }
  } else if (bid < 4352) {
    const float* src; _Float16* dst; size_t i;
    if (bid < 2048)      { src = Wv; dst = Wv16; i = (size_t)(bid - 1024) * 256 + tid; }
    else if (bid < 3072) { src = Wk; dst = Wk16; i = (size_t)(bid - 2048) * 256 + tid; }
    else if (bid < 4096) { src = Wq; dst = Wq16; i = (size_t)(bid - 3072) * 256 + tid; }
    else                 { src = x;  dst = xb;   i = (size_t)(bid - 4096) * 256 + tid; }
    float4 v = ((const float4*)src)[i];
    half4v h = {(_Float16)v.x, (_Float16)v.y, (_Float16)v.z, (_Float16)v.w};
    *(half4v*)(dst + 4 * i) = h;
  } else {
    int tb = bid - 4352;
    int t0 = (tb & 255) * 64, f0 = (tb >> 8) * 64;
    __shared__ _Float16 lt[64][72];
    int r = tid >> 2, c0 = (tid & 3) * 16;
    half8 s0, s1;
#pragma unroll
    for (int i = 0; i < 4; i++) {
      float4 v = *(const float4*)&hist[(size_t)(t0 + r) * 1024 + f0 + c0 + i * 4];
      half4v h = {(_Float16)v.x, (_Float16)v.y, (_Float16)v.z, (_Float16)v.w};
      *(half4v*)&lt[r][c0 + i * 4] = h;
      if (i < 2) { s0[i*4]=h[0]; s0[i*4+1]=h[1]; s0[i*4+2]=h[2]; s0[i*4+3]=h[3]; }
      else { s1[(i-2)*4]=h[0]; s1[(i-2)*4+1]=h[1]; s1[(i-2)*4+2]=h[2]; s1[(i-2)*4+3]=h[3]; }
    }
    *(half8*)&histb[(size_t)(t0 + r) * 1024 + f0 + c0] = s0;
    *(half8*)&histb[(size_t)(t0 + r) * 1024 + f0 + c0 + 8] = s1;
    __syncthreads();
    int fr = tid >> 2, tc0 = (tid & 3) * 16;
    half8 o0, o1;
#pragma unroll
    for (int j = 0; j < 8; j++) { o0[j] = lt[tc0 + j][fr]; o1[j] = lt[tc0 + 8 + j][fr]; }
    *(half8*)&histT[(size_t)(f0 + fr) * TALL + t0 + tc0] = o0;
    *(half8*)&histT[(size_t)(f0 + fr) * TALL + t0 + tc0 + 8] = o1;
  }
}

// ---------------- double-buffered 128x128 GEMM core (XOR-swizzled) --------
__device__ __forceinline__ void gemm_core_db(const _Float16* __restrict__ A, size_t lda,
                                             const _Float16* __restrict__ B, size_t ldb,
                                             int kIters, _Float16* As, _Float16* Bs,
                                             int tid, floatx4 acc[4][4]) {
  int lane = tid & 63, w = tid >> 6;
  int l15 = lane & 15, quad = lane >> 4;
  int wm = (w >> 1) * 64, wn = (w & 1) * 64;
  int swz = ((tid & 3) ^ ((tid >> 3) & 3)) * 8;
  int pch = (quad ^ ((l15 >> 1) & 3)) * 8;
  const char* gA0 = (const char*)(A + (size_t)(tid >> 2) * lda + swz);
  const char* gA1 = (const char*)(A + ((size_t)(tid >> 2) + 64) * lda + swz);
  const char* gB0 = (const char*)(B + (size_t)(tid >> 2) * ldb + swz);
  const char* gB1 = (const char*)(B + ((size_t)(tid >> 2) + 64) * ldb + swz);
  int so = w * 512;
  __syncthreads();
  gl_lds16(gA0, As + so); gl_lds16(gA1, As + 2048 + so);
  gl_lds16(gB0, Bs + so); gl_lds16(gB1, Bs + 2048 + so);
  for (int kk = 0; kk < kIters; kk++) {
    int cur = (kk & 1) * 4096;
    __syncthreads();
    if (kk + 1 < kIters) {
      int nxt = 4096 - cur;
      size_t off = (size_t)(kk + 1) * 64;
      gl_lds16(gA0 + off, As + nxt + so); gl_lds16(gA1 + off, As + nxt + 2048 + so);
      gl_lds16(gB0 + off, Bs + nxt + so); gl_lds16(gB1 + off, Bs + nxt + 2048 + so);
    }
    const _Float16* Ac = As + cur;
    const _Float16* Bc = Bs + cur;
    half8 a[4];
#pragma unroll
    for (int mi = 0; mi < 4; mi++) a[mi] = *(const half8*)&Ac[(wm + mi * 16 + l15) * 32 + pch];
#pragma unroll
    for (int ni = 0; ni < 4; ni++) {
      half8 b8 = *(const half8*)&Bc[(wn + ni * 16 + l15) * 32 + pch];
#pragma unroll
      for (int mi = 0; mi < 4; mi++)
        acc[mi][ni] = __builtin_amdgcn_mfma_f32_16x16x32_f16(a[mi], b8, acc[mi][ni], 0, 0, 0);
    }
  }
}

// ---------------- mega kernel args ----------------
struct MegaArgs {
  const _Float16 *WoT, *Wv16, *Wk16, *Wq16, *xb, *histb, *histT;
  const float *bv, *bq, *bo, *dil_w, *gamma, *beta, *x;
  _Float16 *WVOT, *WQKT, *G, *expS, *phpart, *PHred;
  float *bvwo, *bqk, *cf, *oppart, *out;
  u32 *bar;
};

// ---------------- mega: wpack,G,S+exp,cf,PH(c-fold),red,FO,ln -------------
__global__ __launch_bounds__(256, 2) void mega_kernel(MegaArgs a) {
  __shared__ __align__(16) _Float16 As[8192];
  __shared__ __align__(16) _Float16 Bs[8192];
  int bid = blockIdx.x, tid = threadIdx.x;
  int lane = tid & 63, w = tid >> 6;
  int l15 = lane & 15, quad = lane >> 4;
  int wm = (w >> 1) * 64, wn = (w & 1) * 64;
  floatx4 zero = {0.f, 0.f, 0.f, 0.f};

  // ===== phase 0: wpack (512 gemm jobs + bias dots) =====
  {
    bool isQK = bid >= 256;                 // block-uniform; single MFMA path
    int g = bid & 255;
    int x8 = g & 7, y8 = (g >> 3) & 7, z = g >> 6;
    const _Float16* A = isQK ? a.Wk16 : a.WoT;
    const _Float16* B = isQK ? a.Wq16 : a.Wv16;
    floatx4 acc[4][4];
#pragma unroll
    for (int i = 0; i < 4; i++)
#pragma unroll
      for (int j = 0; j < 4; j++) acc[i][j] = zero;
    gemm_core_db(A + 256 * z + (size_t)(y8 * 128) * 1024,
                 1024, B + 256 * z + (size_t)(x8 * 128) * 1024, 1024, 8, As, Bs, tid, acc);
    float scale = isQK ? 0.0625f : 1.0f;
    _Float16* C = isQK ? a.WQKT : a.WVOT;
    size_t ldc = isQK ? 1024 : 4096;
    size_t zoff = isQK ? (size_t)1048576 * z : (size_t)1024 * z;
#pragma unroll
    for (int mi = 0; mi < 4; mi++)
#pragma unroll
      for (int ni = 0; ni < 4; ni++) {
        int col = x8 * 128 + wn + ni * 16 + l15;
#pragma unroll
        for (int r = 0; r < 4; r++) {
          int row = y8 * 128 + wm + mi * 16 + quad * 4 + r;
          C[zoff + (size_t)row * ldc + col] = (_Float16)(acc[mi][ni][r] * scale);
        }
      }
    if (bid < 4) {
      int j = bid * 256 + tid;
      const half8* row = (const half8*)(a.WoT + (size_t)j * 1024);
      float s = 0.f;
      for (int c = 0; c < 128; c++) {
        half8 w8 = row[c];
#pragma unroll
        for (int e = 0; e < 8; e++) s += a.bv[c * 8 + e] * (float)w8[e];
      }
      a.bvwo[j] = s;
    } else if (bid < 20) {
      int idx = (bid - 4) * 256 + tid;
      int h = idx >> 10, f = idx & 1023;
      const _Float16* row = a.Wk16 + (size_t)f * 1024 + h * 256;
      float s = 0.f;
      for (int n = 0; n < 256; n++) s += a.bq[h * 256 + n] * (float)row[n];
      a.bqk[idx] = s * 0.0625f;
    }
  }
  gsync(a.bar, 512u, tid);

  // ===== phase 1: G[h] = xb @ WQKT_h^T + bqk_h (64 jobs) =====
  if (bid < 64) {
    int x8 = bid & 7, y = (bid >> 3) & 1, h = bid >> 4;
    floatx4 acc[4][4];
#pragma unroll
    for (int i = 0; i < 4; i++)
#pragma unroll
      for (int j = 0; j < 4; j++) acc[i][j] = zero;
    gemm_core_db(a.xb + (size_t)(y * 128) * 1024, 1024,
                 a.WQKT + (size_t)h * 1048576 + (size_t)(x8 * 128) * 1024, 1024,
                 32, As, Bs, tid, acc);
#pragma unroll
    for (int mi = 0; mi < 4; mi++)
#pragma unroll
      for (int ni = 0; ni < 4; ni++) {
        int col = x8 * 128 + wn + ni * 16 + l15;
        float bb = a.bqk[h * 1024 + col];
#pragma unroll
        for (int r = 0; r < 4; r++) {
          int row = y * 128 + wm + mi * 16 + quad * 4 + r;
          a.G[(size_t)h * 262144 + (size_t)row * 1024 + col] = (_Float16)(acc[mi][ni][r] + bb);
        }
      }
  }
  gsync(a.bar, 1024u, tid);

  // ===== phase 2: expS[h] = exp(G_h @ hist^T) (1024 jobs, 2/block) =====
  for (int t = 0; t < 2; t++) {
    int j = bid + t * 512;
    int b7 = j & 7, rr = j >> 3;
    int x8 = ((rr & 15) << 3) | b7;
    int yh = rr >> 4;
    int y = yh & 1, h = yh >> 1;
    floatx4 acc[4][4];
#pragma unroll
    for (int i = 0; i < 4; i++)
#pragma unroll
      for (int jj = 0; jj < 4; jj++) acc[i][jj] = zero;
    gemm_core_db(a.G + (size_t)h * 262144 + (size_t)(y * 128) * 1024, 1024,
                 a.histb + (size_t)(x8 * 128) * 1024, 1024, 32, As, Bs, tid, acc);
#pragma unroll
    for (int mi = 0; mi < 4; mi++)
#pragma unroll
      for (int ni = 0; ni < 4; ni++) {
        int col = x8 * 128 + wn + ni * 16 + l15;
#pragma unroll
        for (int r = 0; r < 4; r++) {
          int row = y * 128 + wm + mi * 16 + quad * 4 + r;
          a.expS[(size_t)h * 4194304 + (size_t)row * TALL + col] = (_Float16)__expf(acc[mi][ni][r]);
        }
      }
  }
  gsync(a.bar, 1536u, tid);

  // ===== phase 3: cf table (1024 rows, 2/block) =====
  {
    float* Zf = (float*)As;        // 64 floats
    float* Zd = Zf + 64;           // 4 floats
    for (int t = 0; t < 2; t++) {
      int r = bid + t * 512;
      const _Float16* row = a.expS + (size_t)r * TALL;
      __syncthreads();
#pragma unroll
      for (int i = 0; i < 8; i++) {
        half8 v = *(const half8*)&row[((size_t)i * 256 + tid) * 8];
        float s = 0.f;
#pragma unroll
        for (int jj = 0; jj < 8; jj++) s += (float)v[jj];
#pragma unroll
        for (int off = 1; off <= 16; off <<= 1) s += __shfl_xor(s, off, 64);
        if ((lane & 31) == 0) Zf[i * 8 + (tid >> 5)] = s;
      }
      __syncthreads();
      if (tid < 4) {
        int step = 1 << (tid + (tid ? 1 : 0));   // 1,4,8,16
        float z = 0.f;
        for (int f = 0; f < 64; f += step) z += Zf[f];
        Zd[tid] = z;
      }
      __syncthreads();
      if (tid < 64) {
        float w0 = a.dil_w[0], w1 = a.dil_w[1], w2 = a.dil_w[2], w3 = a.dil_w[3];
        float wmx = fmaxf(fmaxf(w0, w1), fmaxf(w2, w3));
        float e0 = __expf(w0 - wmx), e1 = __expf(w1 - wmx);
        float e2 = __expf(w2 - wmx), e3 = __expf(w3 - wmx);
        float wsum = e0 + e1 + e2 + e3;
        float c = (e0 / wsum) / Zd[0];
        if ((tid & 3) == 0) c += (e1 / wsum) / Zd[1];
        if ((tid & 7) == 0) c += (e2 / wsum) / Zd[2];
        if ((tid & 15) == 0) c += (e3 / wsum) / Zd[3];
        a.cf[r * 64 + tid] = c;
      }
      __syncthreads();
    }
  }
  gsync(a.bar, 2048u, tid);

  // ===== phase 4: PH with c folded at frame boundaries (1024 jobs) =====
  for (int t = 0; t < 2; t++) {
    int j = bid + t * 512;
    int splo = j & 7, x8 = (j >> 3) & 7, yh = (j >> 6) & 7, sphi = j >> 9;
    int sp = sphi * 8 + splo;
    int y = yh & 1, h = yh >> 1;
    const _Float16* A = a.expS + (size_t)h * 4194304 + (size_t)(y * 128) * TALL + sp * 1024;
    const _Float16* B = a.histT + (size_t)(x8 * 128) * TALL + sp * 1024;
    int swz = ((tid & 3) ^ ((tid >> 3) & 3)) * 8;
    int pch = (quad ^ ((l15 >> 1) & 3)) * 8;
    const char* gA0 = (const char*)(A + (size_t)(tid >> 2) * TALL + swz);
    const char* gA1 = (const char*)(A + ((size_t)(tid >> 2) + 64) * TALL + swz);
    const char* gB0 = (const char*)(B + (size_t)(tid >> 2) * TALL + swz);
    const char* gB1 = (const char*)(B + ((size_t)(tid >> 2) + 64) * TALL + swz);
    int so = w * 512;
    floatx4 acc[4][4];
#pragma unroll
    for (int i = 0; i < 4; i++)
#pragma unroll
      for (int jj = 0; jj < 4; jj++) acc[i][jj] = zero;
    const float* cbase = a.cf + (size_t)(h * 256) * 64;
    __syncthreads();
    gl_lds16(gA0, As + so); gl_lds16(gA1, As + 2048 + so);
    gl_lds16(gB0, Bs + so); gl_lds16(gB1, Bs + 2048 + so);
    for (int kk = 0; kk < 32; kk++) {
      int cur = (kk & 1) * 4096;
      __syncthreads();
      if (kk + 1 < 32) {
        int nxt = 4096 - cur;
        size_t off = (size_t)(kk + 1) * 64;
        gl_lds16(gA0 + off, As + nxt + so); gl_lds16(gA1 + off, As + nxt + 2048 + so);
        gl_lds16(gB0 + off, Bs + nxt + so); gl_lds16(gB1 + off, Bs + nxt + 2048 + so);
      }
      const _Float16* Ac = As + cur;
      const _Float16* Bc = Bs + cur;
      half8 af[4];
#pragma unroll
      for (int mi = 0; mi < 4; mi++) af[mi] = *(const half8*)&Ac[(wm + mi * 16 + l15) * 32 + pch];
#pragma unroll
      for (int ni = 0; ni < 4; ni++) {
        half8 b8 = *(const half8*)&Bc[(wn + ni * 16 + l15) * 32 + pch];
#pragma unroll
        for (int mi = 0; mi < 4; mi++)
          acc[mi][ni] = __builtin_amdgcn_mfma_f32_16x16x32_f16(af[mi], b8, acc[mi][ni], 0, 0, 0);
      }
      if ((kk & 7) == 7) {       // end of frame fi: telescoping c rescale
        int fi = sp * 4 + (kk >> 3);
#pragma unroll
        for (int mi = 0; mi < 4; mi++)
#pragma unroll
          for (int r = 0; r < 4; r++) {
            int q = y * 128 + wm + mi * 16 + quad * 4 + r;
            float cn = cbase[q * 64 + fi];
            float sc = (kk == 31) ? cn : cn / cbase[q * 64 + fi + 1];
#pragma unroll
            for (int ni = 0; ni < 4; ni++) acc[mi][ni][r] *= sc;
          }
      }
    }
#pragma unroll
    for (int mi = 0; mi < 4; mi++)
#pragma unroll
      for (int ni = 0; ni < 4; ni++) {
        int k = x8 * 128 + wn + ni * 16 + l15;
#pragma unroll
        for (int r = 0; r < 4; r++) {
          int q = y * 128 + wm + mi * 16 + quad * 4 + r;
          a.phpart[(size_t)(h * 16 + sp) * 262144 + (size_t)q * 1024 + k] = (_Float16)acc[mi][ni][r];
        }
      }
  }
  gsync(a.bar, 2560u, tid);

  // ===== phase 5: red 16 partials -> PHred (agent-scope loads: alias-safe) =====
  {
    size_t e8 = ((size_t)bid * 256 + tid) * 8;
    int q = (int)(e8 >> 12);
    int hk = (int)(e8 & 4095);
    int h = hk >> 10, k = hk & 1023;
    float s[8] = {0.f, 0.f, 0.f, 0.f, 0.f, 0.f, 0.f, 0.f};
    union { u64 u; _Float16 hx[4]; } cv;
#pragma unroll
    for (int sp = 0; sp < 16; sp++) {
      const u64* p = (const u64*)&a.phpart[(size_t)(h * 16 + sp) * 262144 + (size_t)q * 1024 + k];
      u64 lo = __hip_atomic_load(p, __ATOMIC_RELAXED, __HIP_MEMORY_SCOPE_AGENT);
      u64 hi = __hip_atomic_load(p + 1, __ATOMIC_RELAXED, __HIP_MEMORY_SCOPE_AGENT);
      cv.u = lo;
#pragma unroll
      for (int e = 0; e < 4; e++) s[e] += (float)cv.hx[e];
      cv.u = hi;
#pragma unroll
      for (int e = 0; e < 4; e++) s[4 + e] += (float)cv.hx[e];
    }
    half8 o;
#pragma unroll
    for (int e = 0; e < 8; e++) o[e] = (_Float16)s[e];
    *(half8*)&a.PHred[e8] = o;
  }
  gsync(a.bar, 3072u, tid);

  // ===== phase 6: FO partials = PHred @ WVOT^T (128 jobs, split-K 8) =====
  if (bid < 128) {
    int x8 = bid & 7, y = (bid >> 3) & 1, z = bid >> 4;
    floatx4 acc[4][4];
#pragma unroll
    for (int i = 0; i < 4; i++)
#pragma unroll
      for (int jj = 0; jj < 4; jj++) acc[i][jj] = zero;
    gemm_core_db(a.PHred + (size_t)(y * 128) * 4096 + z * 512, 4096,
                 a.WVOT + (size_t)(x8 * 128) * 4096 + z * 512, 4096, 16, As, Bs, tid, acc);
#pragma unroll
    for (int mi = 0; mi < 4; mi++)
#pragma unroll
      for (int ni = 0; ni < 4; ni++) {
        int col = x8 * 128 + wn + ni * 16 + l15;
#pragma unroll
        for (int r = 0; r < 4; r++) {
          int row = y * 128 + wm + mi * 16 + quad * 4 + r;
          a.oppart[(size_t)z * 262144 + (size_t)row * 1024 + col] = acc[mi][ni][r];
        }
      }
  }
  gsync(a.bar, 3584u, tid);

  // ===== phase 7: ln (256 jobs) =====
  if (bid < 256) {
    int b = bid;
    float* red = (float*)As;
    float y4[4];
    float sum = 0.f, sq = 0.f;
#pragma unroll
    for (int i = 0; i < 4; i++) {
      int j = tid + i * 256;
      float v = a.x[(size_t)b * 1024 + j] + a.bo[j] + a.bvwo[j];
#pragma unroll
      for (int z = 0; z < 8; z++) v += a.oppart[(size_t)z * 262144 + (size_t)b * 1024 + j];
      y4[i] = v;
      sum += v;
      sq += v * v;
    }
#pragma unroll
    for (int off = 1; off < 64; off <<= 1) {
      sum += __shfl_xor(sum, off, 64);
      sq += __shfl_xor(sq, off, 64);
    }
    __syncthreads();
    if (lane == 0) { red[w] = sum; red[4 + w] = sq; }
    __syncthreads();
    sum = red[0] + red[1] + red[2] + red[3];
    sq = red[4] + red[5] + red[6] + red[7];
    float mu = sum * (1.f / 1024.f);
    float var = sq * (1.f / 1024.f) - mu * mu;
    float inv = rsqrtf(var + 1e-5f);
#pragma unroll
    for (int i = 0; i < 4; i++) {
      int j = tid + i * 256;
      a.out[(size_t)b * 1024 + j] = (y4[i] - mu) * inv * a.gamma[j] + a.beta[j];
    }
  }
}

// ---------------- host launch ----------------
extern "C" void kernel_launch(void* const* d_in, const int* in_sizes, int n_in,
                              void* d_out, int out_size, void* d_ws, size_t ws_size,
                              hipStream_t stream) {
  const float* x     = (const float*)d_in[0];
  const float* hist  = (const float*)d_in[1];
  const float* Wq    = (const float*)d_in[2];
  const float* bq    = (const float*)d_in[3];
  const float* Wk    = (const float*)d_in[4];
  // bk (d_in[5]) dropped exactly: softmax shift invariance.
  const float* Wv    = (const float*)d_in[6];
  const float* bv    = (const float*)d_in[7];
  const float* Wo    = (const float*)d_in[8];
  const float* bo    = (const float*)d_in[9];
  const float* dil_w = (const float*)d_in[10];
  const float* gamma = (const float*)d_in[11];
  const float* beta  = (const float*)d_in[12];
  char* ws = (char*)d_ws;

  _Float16* WoT   = (_Float16*)(ws + OFF_WOT);
  _Float16* Wv16  = (_Float16*)(ws + OFF_WV16);
  _Float16* Wk16  = (_Float16*)(ws + OFF_WK16);
  _Float16* Wq16  = (_Float16*)(ws + OFF_WQ16);
  _Float16* xb    = (_Float16*)(ws + OFF_XB);
  _Float16* histb = (_Float16*)(ws + OFF_HB);
  _Float16* histT = (_Float16*)(ws + OFF_HT);

  // 0) zero the grid-barrier counter (ws is re-poisoned before every launch)
  hipMemsetAsync((void*)(ws + OFF_BAR), 0, 64, stream);

  // 1) prep: WoT, Wv/Wk/Wq/x cvt, hist -> histb + histT
  prep_kernel<<<dim3(8448), 256, 0, stream>>>(Wo, Wv, Wk, Wq, x, hist,
                                              WoT, Wv16, Wk16, Wq16, xb, histb, histT);

  // 2) mega kernel (plain launch, manual grid barriers)
  MegaArgs margs;
  margs.WoT = WoT; margs.Wv16 = Wv16; margs.Wk16 = Wk16; margs.Wq16 = Wq16;
  margs.xb = xb; margs.histb = histb; margs.histT = histT;
  margs.bv = bv; margs.bq = bq; margs.bo = bo; margs.dil_w = dil_w;
  margs.gamma = gamma; margs.beta = beta; margs.x = x;
  margs.WVOT  = (_Float16*)(ws + OFF_WVOT);
  margs.WQKT  = (_Float16*)(ws + OFF_WQKT);
  margs.G     = (_Float16*)(ws + OFF_G);
  margs.expS  = (_Float16*)(ws + OFF_S);
  margs.phpart= (_Float16*)(ws + OFF_HB);   // aliases histb (dead after phase 2)
  margs.PHred = (_Float16*)(ws + OFF_PHR);
  margs.bvwo  = (float*)(ws + OFF_BVWO);
  margs.bqk   = (float*)(ws + OFF_BQK);
  margs.cf    = (float*)(ws + OFF_CF);
  margs.oppart= (float*)(ws + OFF_OPP);
  margs.out   = (float*)d_out;
  margs.bar   = (u32*)(ws + OFF_BAR);
  mega_kernel<<<dim3(512), 256, 0, stream>>>(margs);
}